// Round 1
// baseline (30436.023 us; speedup 1.0000x reference)
//
#include <hip/hip_runtime.h>

#define DT 5e-5f
#define SPRING_Y 30000.0f
#define DASHPOT 100.0f
// exp(-DT * DRAG_DAMPING) = exp(-5e-5)
#define DRAG 0.9999500012499792f

__global__ void init_k(const float* __restrict__ x0, float* __restrict__ x,
                       float* __restrict__ v, float* __restrict__ f, int n3) {
    int i = blockIdx.x * blockDim.x + threadIdx.x;
    if (i < n3) {
        x[i] = x0[i];
        v[i] = 0.0f;
        f[i] = 0.0f;
    }
}

__global__ void spring_k(const float* __restrict__ x, const float* __restrict__ v,
                         const int* __restrict__ springs, const float* __restrict__ rest,
                         float* __restrict__ f, int ns) {
    int s = blockIdx.x * blockDim.x + threadIdx.x;
    if (s >= ns) return;
    int i1 = springs[2 * s];
    int i2 = springs[2 * s + 1];
    float r = rest[s];

    float dx = x[3 * i2 + 0] - x[3 * i1 + 0];
    float dy = x[3 * i2 + 1] - x[3 * i1 + 1];
    float dz = x[3 * i2 + 2] - x[3 * i1 + 2];
    float len = sqrtf(dx * dx + dy * dy + dz * dz);
    float invLen = 1.0f / len;
    float ddx = dx * invLen, ddy = dy * invLen, ddz = dz * invLen;

    float dvx = v[3 * i2 + 0] - v[3 * i1 + 0];
    float dvy = v[3 * i2 + 1] - v[3 * i1 + 1];
    float dvz = v[3 * i2 + 2] - v[3 * i1 + 2];
    float vrel = dvx * ddx + dvy * ddy + dvz * ddz;

    float coef = SPRING_Y * (len / r - 1.0f) + DASHPOT * vrel;
    float fx = coef * ddx, fy = coef * ddy, fz = coef * ddz;

    atomicAdd(&f[3 * i1 + 0], fx);
    atomicAdd(&f[3 * i1 + 1], fy);
    atomicAdd(&f[3 * i1 + 2], fz);
    atomicAdd(&f[3 * i2 + 0], -fx);
    atomicAdd(&f[3 * i2 + 1], -fy);
    atomicAdd(&f[3 * i2 + 2], -fz);
}

__global__ void vertex_k(float* __restrict__ x, float* __restrict__ v,
                         float* __restrict__ f, const float* __restrict__ m, int nv) {
    int i = blockIdx.x * blockDim.x + threadIdx.x;
    if (i >= nv) return;
    float mass = m[i];
    float inv = 1.0f / mass;

    float fx = f[3 * i + 0];
    float fy = f[3 * i + 1];
    float fz = f[3 * i + 2];
    // reset accumulator for the next substep
    f[3 * i + 0] = 0.0f;
    f[3 * i + 1] = 0.0f;
    f[3 * i + 2] = 0.0f;

    // forces = masses*gravity + scattered spring forces; v = (v + DT*F/m)*drag
    fz += mass * (-9.8f);

    float vx = (v[3 * i + 0] + DT * fx * inv) * DRAG;
    float vy = (v[3 * i + 1] + DT * fy * inv) * DRAG;
    float vz = (v[3 * i + 2] + DT * fz * inv) * DRAG;

    float xx = x[3 * i + 0] + DT * vx;
    float xy = x[3 * i + 1] + DT * vy;
    float xz = x[3 * i + 2] + DT * vz;

    xz = fmaxf(xz, 0.0f);
    if (xz == 0.0f) vz = 0.0f;

    x[3 * i + 0] = xx;
    x[3 * i + 1] = xy;
    x[3 * i + 2] = xz;
    v[3 * i + 0] = vx;
    v[3 * i + 1] = vy;
    v[3 * i + 2] = vz;
}

extern "C" void kernel_launch(void* const* d_in, const int* in_sizes, int n_in,
                              void* d_out, int out_size, void* d_ws, size_t ws_size,
                              hipStream_t stream) {
    const float* x0      = (const float*)d_in[0];   // (NV,3) fp32
    const int*   springs = (const int*)d_in[1];     // (NS,2) int
    const float* rest    = (const float*)d_in[2];   // (NS,)  fp32
    const float* mass    = (const float*)d_in[3];   // (NV,)  fp32

    const int ns = in_sizes[2];        // 1,000,000
    const int nv = in_sizes[3];        // 100,000
    const int n3 = 3 * nv;

    float* x = (float*)d_out;          // positions live in d_out
    float* v = (float*)d_ws;           // velocities
    float* f = v + n3;                 // force accumulator

    init_k<<<(n3 + 255) / 256, 256, 0, stream>>>(x0, x, v, f, n3);

    const int NSUB = 100;
    dim3 sgrid((ns + 255) / 256), vgrid((nv + 255) / 256), blk(256);
    for (int t = 0; t < NSUB; ++t) {
        spring_k<<<sgrid, blk, 0, stream>>>(x, v, springs, rest, f, ns);
        vertex_k<<<vgrid, blk, 0, stream>>>(x, v, f, mass, nv);
    }
}

// Round 2
// 6371.326 us; speedup vs baseline: 4.7770x; 4.7770x over previous
//
#include <hip/hip_runtime.h>

#define DT 5e-5f
#define SPRING_Y 30000.0f
#define DASHPOT 100.0f
// exp(-DT * DRAG_DAMPING) = exp(-5e-5)
#define DRAG 0.9999500012499792f

// ---------- one-time (per launch) CSR build ----------

__global__ void init_k(const float* __restrict__ x0, float4* __restrict__ x4,
                       float4* __restrict__ v4, int* __restrict__ deg, int nv) {
    int i = blockIdx.x * blockDim.x + threadIdx.x;
    if (i < nv) {
        x4[i] = make_float4(x0[3 * i], x0[3 * i + 1], x0[3 * i + 2], 0.0f);
        v4[i] = make_float4(0.0f, 0.0f, 0.0f, 0.0f);
        deg[i] = 0;
    }
}

__global__ void count_k(const int2* __restrict__ springs, int* __restrict__ deg, int ns) {
    int s = blockIdx.x * blockDim.x + threadIdx.x;
    if (s < ns) {
        int2 p = springs[s];
        atomicAdd(&deg[p.x], 1);
        atomicAdd(&deg[p.y], 1);
    }
}

// single-block exclusive scan over nv degrees -> offsets (+ cursor copy)
__global__ void scan_k(const int* __restrict__ deg, int* __restrict__ off,
                       int* __restrict__ cursor, int nv) {
    __shared__ int part[1024];
    const int tid = threadIdx.x;
    const int T = blockDim.x;
    const int chunk = (nv + T - 1) / T;
    const int base = tid * chunk;

    int sum = 0;
    for (int i = 0; i < chunk; ++i) {
        int j = base + i;
        if (j < nv) sum += deg[j];
    }
    part[tid] = sum;
    __syncthreads();
    // Hillis-Steele inclusive scan over the T partials
    for (int d = 1; d < T; d <<= 1) {
        int val = (tid >= d) ? part[tid - d] : 0;
        __syncthreads();
        part[tid] += val;
        __syncthreads();
    }
    int run = (tid == 0) ? 0 : part[tid - 1];
    for (int i = 0; i < chunk; ++i) {
        int j = base + i;
        if (j < nv) {
            off[j] = run;
            cursor[j] = run;
            run += deg[j];
        }
    }
    if (tid == T - 1) off[nv] = run;
}

__global__ void fill_k(const int2* __restrict__ springs, int* __restrict__ cursor,
                       int* __restrict__ adj, int ns) {
    int s = blockIdx.x * blockDim.x + threadIdx.x;
    if (s < ns) {
        int2 p = springs[s];
        int a = atomicAdd(&cursor[p.x], 1);
        adj[a] = (s << 1);          // this vertex is idx1 -> +f_pair
        int b = atomicAdd(&cursor[p.y], 1);
        adj[b] = (s << 1) | 1;      // this vertex is idx2 -> -f_pair
    }
}

// ---------- per-substep kernels ----------

__global__ void force_k(const float4* __restrict__ x4, const float4* __restrict__ v4,
                        const int2* __restrict__ springs, const float* __restrict__ rest,
                        float4* __restrict__ fpair, int ns) {
    int s = blockIdx.x * blockDim.x + threadIdx.x;
    if (s >= ns) return;
    int2 p = springs[s];
    float4 xa = x4[p.x];
    float4 xb = x4[p.y];
    float4 va = v4[p.x];
    float4 vb = v4[p.y];

    float dx = xb.x - xa.x, dy = xb.y - xa.y, dz = xb.z - xa.z;
    float len = sqrtf(dx * dx + dy * dy + dz * dz);
    float inv = 1.0f / len;
    float ddx = dx * inv, ddy = dy * inv, ddz = dz * inv;

    float vrel = (vb.x - va.x) * ddx + (vb.y - va.y) * ddy + (vb.z - va.z) * ddz;
    float coef = SPRING_Y * (len / rest[s] - 1.0f) + DASHPOT * vrel;

    fpair[s] = make_float4(coef * ddx, coef * ddy, coef * ddz, 0.0f);
}

__global__ void integrate_k(float4* __restrict__ x4, float4* __restrict__ v4,
                            const float4* __restrict__ fpair, const int* __restrict__ off,
                            const int* __restrict__ adj, const float* __restrict__ mass,
                            int nv) {
    int i = blockIdx.x * blockDim.x + threadIdx.x;
    if (i >= nv) return;
    int s0 = off[i], s1 = off[i + 1];
    float fx = 0.0f, fy = 0.0f, fz = 0.0f;
    for (int j = s0; j < s1; ++j) {
        int e = adj[j];
        float4 fp = fpair[e >> 1];
        float sgn = (e & 1) ? -1.0f : 1.0f;
        fx += sgn * fp.x;
        fy += sgn * fp.y;
        fz += sgn * fp.z;
    }
    float m = mass[i];
    fz += m * (-9.8f);
    float invm = 1.0f / m;

    float4 v = v4[i];
    v.x = (v.x + DT * fx * invm) * DRAG;
    v.y = (v.y + DT * fy * invm) * DRAG;
    v.z = (v.z + DT * fz * invm) * DRAG;

    float4 x = x4[i];
    x.x += DT * v.x;
    x.y += DT * v.y;
    x.z += DT * v.z;
    x.z = fmaxf(x.z, 0.0f);
    if (x.z == 0.0f) v.z = 0.0f;

    x4[i] = x;
    v4[i] = v;
}

__global__ void pack_k(const float4* __restrict__ x4, float* __restrict__ out, int nv) {
    int i = blockIdx.x * blockDim.x + threadIdx.x;
    if (i < nv) {
        float4 x = x4[i];
        out[3 * i + 0] = x.x;
        out[3 * i + 1] = x.y;
        out[3 * i + 2] = x.z;
    }
}

extern "C" void kernel_launch(void* const* d_in, const int* in_sizes, int n_in,
                              void* d_out, int out_size, void* d_ws, size_t ws_size,
                              hipStream_t stream) {
    const float* x0      = (const float*)d_in[0];   // (NV,3) fp32
    const int2*  springs = (const int2*)d_in[1];    // (NS,2) int32
    const float* rest    = (const float*)d_in[2];   // (NS,)  fp32
    const float* mass    = (const float*)d_in[3];   // (NV,)  fp32

    const int ns = in_sizes[2];        // 1,000,000
    const int nv = in_sizes[3];        // 100,000

    // workspace layout (16B-aligned sections)
    char* ws = (char*)d_ws;
    size_t o = 0;
    float4* fpair = (float4*)(ws + o); o += (size_t)ns * 16;                 // 16 MB
    float4* x4    = (float4*)(ws + o); o += (size_t)nv * 16;                 // 1.6 MB
    float4* v4    = (float4*)(ws + o); o += (size_t)nv * 16;                 // 1.6 MB
    int* deg      = (int*)(ws + o);    o += (((size_t)nv * 4 + 15) & ~15ull);
    int* off      = (int*)(ws + o);    o += ((((size_t)nv + 1) * 4 + 15) & ~15ull);
    int* cursor   = (int*)(ws + o);    o += (((size_t)nv * 4 + 15) & ~15ull);
    int* adj      = (int*)(ws + o);    o += (size_t)ns * 2 * 4;              // 8 MB

    dim3 blk(256);
    dim3 vgrid((nv + 255) / 256);
    dim3 sgrid((ns + 255) / 256);

    // one-time build (replayed every call; amortized over 100 substeps)
    init_k<<<vgrid, blk, 0, stream>>>(x0, x4, v4, deg, nv);
    count_k<<<sgrid, blk, 0, stream>>>(springs, deg, ns);
    scan_k<<<1, 1024, 0, stream>>>(deg, off, cursor, nv);
    fill_k<<<sgrid, blk, 0, stream>>>(springs, cursor, adj, ns);

    const int NSUB = 100;
    for (int t = 0; t < NSUB; ++t) {
        force_k<<<sgrid, blk, 0, stream>>>(x4, v4, springs, rest, fpair, ns);
        integrate_k<<<vgrid, blk, 0, stream>>>(x4, v4, fpair, off, adj, mass, nv);
    }
    pack_k<<<vgrid, blk, 0, stream>>>(x4, (float*)d_out, nv);
}

// Round 3
// 5078.508 us; speedup vs baseline: 5.9931x; 1.2546x over previous
//
#include <hip/hip_runtime.h>

#define DT 5e-5f
#define SPRING_Y 30000.0f
#define DASHPOT 100.0f
// exp(-DT * DRAG_DAMPING) = exp(-5e-5)
#define DRAG 0.9999500012499792f

// ---------- one-time (per launch) CSR build ----------

__global__ void init_k(const float* __restrict__ x0, float4* __restrict__ x4,
                       float4* __restrict__ v4, int* __restrict__ deg, int nv) {
    int i = blockIdx.x * blockDim.x + threadIdx.x;
    if (i < nv) {
        x4[i] = make_float4(x0[3 * i], x0[3 * i + 1], x0[3 * i + 2], 0.0f);
        v4[i] = make_float4(0.0f, 0.0f, 0.0f, 0.0f);
        deg[i] = 0;
    }
}

__global__ void count_k(const int2* __restrict__ springs, int* __restrict__ deg, int ns) {
    int s = blockIdx.x * blockDim.x + threadIdx.x;
    if (s < ns) {
        int2 p = springs[s];
        atomicAdd(&deg[p.x], 1);
        atomicAdd(&deg[p.y], 1);
    }
}

// 3-phase block scan: per-block exclusive scan + block totals
__global__ void scan1_k(const int* __restrict__ deg, int* __restrict__ off,
                        int* __restrict__ partials, int nv) {
    __shared__ int sh[256];
    int t = threadIdx.x;
    int g = blockIdx.x * 256 + t;
    int v = (g < nv) ? deg[g] : 0;
    sh[t] = v;
    __syncthreads();
    for (int d = 1; d < 256; d <<= 1) {
        int x = (t >= d) ? sh[t - d] : 0;
        __syncthreads();
        sh[t] += x;
        __syncthreads();
    }
    if (g < nv) off[g] = sh[t] - v;           // exclusive within block
    if (t == 255) partials[blockIdx.x] = sh[255];
}

// scan the block totals (nb <= 512), write grand total to off[nv]
__global__ void scan2_k(int* __restrict__ partials, int* __restrict__ off_nv, int nb) {
    __shared__ int sh[512];
    int t = threadIdx.x;
    int v = (t < nb) ? partials[t] : 0;
    sh[t] = v;
    __syncthreads();
    for (int d = 1; d < 512; d <<= 1) {
        int x = (t >= d) ? sh[t - d] : 0;
        __syncthreads();
        sh[t] += x;
        __syncthreads();
    }
    if (t < nb) partials[t] = sh[t] - v;      // exclusive block offsets
    if (t == 511) *off_nv = sh[511];          // total (= 2*ns)
}

__global__ void scan3_k(int* __restrict__ off, int* __restrict__ cursor,
                        const int* __restrict__ partials, int nv) {
    int g = blockIdx.x * 256 + threadIdx.x;
    if (g < nv) {
        int o = off[g] + partials[blockIdx.x];
        off[g] = o;
        cursor[g] = o;
    }
}

// adjacency entry: (neighbor index, 1/rest as bits) — force formula is
// symmetric in the two endpoints, so no sign is needed.
__global__ void fill_k(const int2* __restrict__ springs, const float* __restrict__ rest,
                       int* __restrict__ cursor, int2* __restrict__ adj, int ns) {
    int s = blockIdx.x * blockDim.x + threadIdx.x;
    if (s < ns) {
        int2 p = springs[s];
        int ir = __float_as_int(1.0f / rest[s]);
        int a = atomicAdd(&cursor[p.x], 1);
        adj[a] = make_int2(p.y, ir);
        int b = atomicAdd(&cursor[p.y], 1);
        adj[b] = make_int2(p.x, ir);
    }
}

// ---------- fused per-substep kernel (vertex-centric, ping-pong) ----------

__global__ void substep_k(const float4* __restrict__ xin, const float4* __restrict__ vin,
                          float4* __restrict__ xout, float4* __restrict__ vout,
                          const int2* __restrict__ adj, const int* __restrict__ off,
                          const float* __restrict__ mass, int nv) {
    int i = blockIdx.x * blockDim.x + threadIdx.x;
    if (i >= nv) return;
    float4 xa = xin[i];
    float4 va = vin[i];
    int s0 = off[i], s1 = off[i + 1];

    float fx = 0.0f, fy = 0.0f, fz = 0.0f;
    for (int j = s0; j < s1; ++j) {
        int2 e = adj[j];
        float4 xb = xin[e.x];
        float4 vb = vin[e.x];
        float invr = __int_as_float(e.y);

        float dx = xb.x - xa.x, dy = xb.y - xa.y, dz = xb.z - xa.z;
        float len = sqrtf(dx * dx + dy * dy + dz * dz);
        float il = 1.0f / len;
        float ddx = dx * il, ddy = dy * il, ddz = dz * il;

        float vrel = (vb.x - va.x) * ddx + (vb.y - va.y) * ddy + (vb.z - va.z) * ddz;
        float coef = SPRING_Y * (len * invr - 1.0f) + DASHPOT * vrel;

        fx += coef * ddx;
        fy += coef * ddy;
        fz += coef * ddz;
    }

    float m = mass[i];
    fz += m * (-9.8f);
    float invm = 1.0f / m;

    va.x = (va.x + DT * fx * invm) * DRAG;
    va.y = (va.y + DT * fy * invm) * DRAG;
    va.z = (va.z + DT * fz * invm) * DRAG;

    xa.x += DT * va.x;
    xa.y += DT * va.y;
    xa.z += DT * va.z;
    xa.z = fmaxf(xa.z, 0.0f);
    if (xa.z == 0.0f) va.z = 0.0f;

    xout[i] = xa;
    vout[i] = va;
}

__global__ void pack_k(const float4* __restrict__ x4, float* __restrict__ out, int nv) {
    int i = blockIdx.x * blockDim.x + threadIdx.x;
    if (i < nv) {
        float4 x = x4[i];
        out[3 * i + 0] = x.x;
        out[3 * i + 1] = x.y;
        out[3 * i + 2] = x.z;
    }
}

extern "C" void kernel_launch(void* const* d_in, const int* in_sizes, int n_in,
                              void* d_out, int out_size, void* d_ws, size_t ws_size,
                              hipStream_t stream) {
    const float* x0      = (const float*)d_in[0];   // (NV,3) fp32
    const int2*  springs = (const int2*)d_in[1];    // (NS,2) int32
    const float* rest    = (const float*)d_in[2];   // (NS,)  fp32
    const float* mass    = (const float*)d_in[3];   // (NV,)  fp32

    const int ns = in_sizes[2];        // 1,000,000
    const int nv = in_sizes[3];        // 100,000
    const int nb = (nv + 255) / 256;   // 391 blocks

    // workspace layout (16B-aligned sections)
    char* ws = (char*)d_ws;
    size_t o = 0;
    float4* x4a = (float4*)(ws + o); o += (size_t)nv * 16;
    float4* x4b = (float4*)(ws + o); o += (size_t)nv * 16;
    float4* v4a = (float4*)(ws + o); o += (size_t)nv * 16;
    float4* v4b = (float4*)(ws + o); o += (size_t)nv * 16;
    int* deg      = (int*)(ws + o);  o += (((size_t)nv * 4 + 15) & ~15ull);
    int* off      = (int*)(ws + o);  o += ((((size_t)nv + 1) * 4 + 15) & ~15ull);
    int* cursor   = (int*)(ws + o);  o += (((size_t)nv * 4 + 15) & ~15ull);
    int* partials = (int*)(ws + o);  o += (((size_t)nb * 4 + 15) & ~15ull);
    int2* adj     = (int2*)(ws + o); o += (size_t)ns * 2 * 8;   // 16 MB

    dim3 blk(256);
    dim3 vgrid(nb);
    dim3 sgrid((ns + 255) / 256);

    // one-time build (replayed every call; amortized over 100 substeps)
    init_k<<<vgrid, blk, 0, stream>>>(x0, x4a, v4a, deg, nv);
    count_k<<<sgrid, blk, 0, stream>>>(springs, deg, ns);
    scan1_k<<<vgrid, blk, 0, stream>>>(deg, off, partials, nv);
    scan2_k<<<1, 512, 0, stream>>>(partials, off + nv, nb);
    scan3_k<<<vgrid, blk, 0, stream>>>(off, cursor, partials, nv);
    fill_k<<<sgrid, blk, 0, stream>>>(springs, rest, cursor, adj, ns);

    const int NSUB = 100;
    float4* xi = x4a; float4* vi = v4a;
    float4* xo = x4b; float4* vo = v4b;
    for (int t = 0; t < NSUB; ++t) {
        substep_k<<<vgrid, blk, 0, stream>>>(xi, vi, xo, vo, adj, off, mass, nv);
        float4* tx = xi; xi = xo; xo = tx;
        float4* tv = vi; vi = vo; vo = tv;
    }
    pack_k<<<vgrid, blk, 0, stream>>>(xi, (float*)d_out, nv);
}

// Round 4
// 2725.321 us; speedup vs baseline: 11.1679x; 1.8635x over previous
//
#include <hip/hip_runtime.h>

#define DT 5e-5f
#define SPRING_Y 30000.0f
#define DASHPOT 100.0f
// exp(-DT * DRAG_DAMPING) = exp(-5e-5)
#define DRAG 0.9999500012499792f

// xv layout: xv[2*i] = position (w unused), xv[2*i+1] = velocity (w unused).
// 32B per vertex -> both gathers for a neighbor hit the same 64B line.

// ---------- one-time (per launch) CSR build ----------

__global__ void init_k(const float* __restrict__ x0, float4* __restrict__ xv,
                       int* __restrict__ deg, int nv) {
    int i = blockIdx.x * blockDim.x + threadIdx.x;
    if (i < nv) {
        xv[2 * i]     = make_float4(x0[3 * i], x0[3 * i + 1], x0[3 * i + 2], 0.0f);
        xv[2 * i + 1] = make_float4(0.0f, 0.0f, 0.0f, 0.0f);
        deg[i] = 0;
    }
}

__global__ void count_k(const int2* __restrict__ springs, int* __restrict__ deg, int ns) {
    int s = blockIdx.x * blockDim.x + threadIdx.x;
    if (s < ns) {
        int2 p = springs[s];
        atomicAdd(&deg[p.x], 1);
        atomicAdd(&deg[p.y], 1);
    }
}

// 3-phase block scan: per-block exclusive scan + block totals
__global__ void scan1_k(const int* __restrict__ deg, int* __restrict__ off,
                        int* __restrict__ partials, int nv) {
    __shared__ int sh[256];
    int t = threadIdx.x;
    int g = blockIdx.x * 256 + t;
    int v = (g < nv) ? deg[g] : 0;
    sh[t] = v;
    __syncthreads();
    for (int d = 1; d < 256; d <<= 1) {
        int x = (t >= d) ? sh[t - d] : 0;
        __syncthreads();
        sh[t] += x;
        __syncthreads();
    }
    if (g < nv) off[g] = sh[t] - v;           // exclusive within block
    if (t == 255) partials[blockIdx.x] = sh[255];
}

__global__ void scan2_k(int* __restrict__ partials, int* __restrict__ off_nv, int nb) {
    __shared__ int sh[512];
    int t = threadIdx.x;
    int v = (t < nb) ? partials[t] : 0;
    sh[t] = v;
    __syncthreads();
    for (int d = 1; d < 512; d <<= 1) {
        int x = (t >= d) ? sh[t - d] : 0;
        __syncthreads();
        sh[t] += x;
        __syncthreads();
    }
    if (t < nb) partials[t] = sh[t] - v;      // exclusive block offsets
    if (t == 511) *off_nv = sh[511];          // total (= 2*ns)
}

__global__ void scan3_k(int* __restrict__ off, int* __restrict__ cursor,
                        const int* __restrict__ partials, int nv) {
    int g = blockIdx.x * 256 + threadIdx.x;
    if (g < nv) {
        int o = off[g] + partials[blockIdx.x];
        off[g] = o;
        cursor[g] = o;
    }
}

// adjacency entry: (neighbor index, 1/rest as bits) — force formula is
// symmetric in the two endpoints, so no sign is needed.
__global__ void fill_k(const int2* __restrict__ springs, const float* __restrict__ rest,
                       int* __restrict__ cursor, int2* __restrict__ adj, int ns) {
    int s = blockIdx.x * blockDim.x + threadIdx.x;
    if (s < ns) {
        int2 p = springs[s];
        int ir = __float_as_int(1.0f / rest[s]);
        int a = atomicAdd(&cursor[p.x], 1);
        adj[a] = make_int2(p.y, ir);
        int b = atomicAdd(&cursor[p.y], 1);
        adj[b] = make_int2(p.x, ir);
    }
}

// ---------- fused per-substep kernel: 4 lanes per vertex ----------

__global__ void substep_k(const float4* __restrict__ xvin, float4* __restrict__ xvout,
                          const int2* __restrict__ adj, const int* __restrict__ off,
                          const float* __restrict__ mass, int nv) {
    int gid = blockIdx.x * blockDim.x + threadIdx.x;
    int vid = gid >> 2;
    int sub = gid & 3;
    if (vid >= nv) return;

    float4 xa = xvin[2 * vid];
    float4 va = xvin[2 * vid + 1];
    int s0 = off[vid], s1 = off[vid + 1];

    float fx = 0.0f, fy = 0.0f, fz = 0.0f;
    for (int j = s0 + sub; j < s1; j += 4) {
        int2 e = adj[j];
        float4 xb = xvin[2 * e.x];
        float4 vb = xvin[2 * e.x + 1];
        float invr = __int_as_float(e.y);

        float dx = xb.x - xa.x, dy = xb.y - xa.y, dz = xb.z - xa.z;
        float len = sqrtf(dx * dx + dy * dy + dz * dz);
        float il = 1.0f / len;
        float ddx = dx * il, ddy = dy * il, ddz = dz * il;

        float vrel = (vb.x - va.x) * ddx + (vb.y - va.y) * ddy + (vb.z - va.z) * ddz;
        float coef = SPRING_Y * (len * invr - 1.0f) + DASHPOT * vrel;

        fx += coef * ddx;
        fy += coef * ddy;
        fz += coef * ddz;
    }

    // reduce across the 4 lanes of this vertex (xor stays within the group)
    fx += __shfl_xor(fx, 1);
    fx += __shfl_xor(fx, 2);
    fy += __shfl_xor(fy, 1);
    fy += __shfl_xor(fy, 2);
    fz += __shfl_xor(fz, 1);
    fz += __shfl_xor(fz, 2);

    if (sub == 0) {
        float m = mass[vid];
        fz += m * (-9.8f);
        float invm = 1.0f / m;

        va.x = (va.x + DT * fx * invm) * DRAG;
        va.y = (va.y + DT * fy * invm) * DRAG;
        va.z = (va.z + DT * fz * invm) * DRAG;

        xa.x += DT * va.x;
        xa.y += DT * va.y;
        xa.z += DT * va.z;
        xa.z = fmaxf(xa.z, 0.0f);
        if (xa.z == 0.0f) va.z = 0.0f;

        xvout[2 * vid]     = xa;
        xvout[2 * vid + 1] = va;
    }
}

__global__ void pack_k(const float4* __restrict__ xv, float* __restrict__ out, int nv) {
    int i = blockIdx.x * blockDim.x + threadIdx.x;
    if (i < nv) {
        float4 x = xv[2 * i];
        out[3 * i + 0] = x.x;
        out[3 * i + 1] = x.y;
        out[3 * i + 2] = x.z;
    }
}

extern "C" void kernel_launch(void* const* d_in, const int* in_sizes, int n_in,
                              void* d_out, int out_size, void* d_ws, size_t ws_size,
                              hipStream_t stream) {
    const float* x0      = (const float*)d_in[0];   // (NV,3) fp32
    const int2*  springs = (const int2*)d_in[1];    // (NS,2) int32
    const float* rest    = (const float*)d_in[2];   // (NS,)  fp32
    const float* mass    = (const float*)d_in[3];   // (NV,)  fp32

    const int ns = in_sizes[2];        // 1,000,000
    const int nv = in_sizes[3];        // 100,000
    const int nb = (nv + 255) / 256;   // 391 blocks

    // workspace layout (16B-aligned sections)
    char* ws = (char*)d_ws;
    size_t o = 0;
    float4* xva = (float4*)(ws + o); o += (size_t)nv * 32;   // x,v interleaved
    float4* xvb = (float4*)(ws + o); o += (size_t)nv * 32;
    int* deg      = (int*)(ws + o);  o += (((size_t)nv * 4 + 15) & ~15ull);
    int* off      = (int*)(ws + o);  o += ((((size_t)nv + 1) * 4 + 15) & ~15ull);
    int* cursor   = (int*)(ws + o);  o += (((size_t)nv * 4 + 15) & ~15ull);
    int* partials = (int*)(ws + o);  o += (((size_t)nb * 4 + 15) & ~15ull);
    int2* adj     = (int2*)(ws + o); o += (size_t)ns * 2 * 8;   // 16 MB

    dim3 blk(256);
    dim3 vgrid(nb);
    dim3 sgrid((ns + 255) / 256);
    dim3 subgrid(((size_t)nv * 4 + 255) / 256);   // 4 lanes per vertex

    // one-time build (replayed every call; amortized over 100 substeps)
    init_k<<<vgrid, blk, 0, stream>>>(x0, xva, deg, nv);
    count_k<<<sgrid, blk, 0, stream>>>(springs, deg, ns);
    scan1_k<<<vgrid, blk, 0, stream>>>(deg, off, partials, nv);
    scan2_k<<<1, 512, 0, stream>>>(partials, off + nv, nb);
    scan3_k<<<vgrid, blk, 0, stream>>>(off, cursor, partials, nv);
    fill_k<<<sgrid, blk, 0, stream>>>(springs, rest, cursor, adj, ns);

    const int NSUB = 100;
    float4* xi = xva;
    float4* xo = xvb;
    for (int t = 0; t < NSUB; ++t) {
        substep_k<<<subgrid, blk, 0, stream>>>(xi, xo, adj, off, mass, nv);
        float4* tmp = xi; xi = xo; xo = tmp;
    }
    pack_k<<<vgrid, blk, 0, stream>>>(xi, (float*)d_out, nv);
}